// Round 1
// baseline (152.410 us; speedup 1.0000x reference)
//
#include <hip/hip_runtime.h>

// ---------- bf16 <-> f32 helpers (raw ushort representation) ----------
__device__ __forceinline__ float b2f(unsigned short h) {
    unsigned int u = ((unsigned int)h) << 16;
    return __builtin_bit_cast(float, u);
}
__device__ __forceinline__ unsigned short f2b(float f) {
    unsigned int u = __builtin_bit_cast(unsigned int, f);
    u += 0x7fffu + ((u >> 16) & 1u);   // round-to-nearest-even
    return (unsigned short)(u >> 16);
}

typedef short bf16x8_t __attribute__((ext_vector_type(8)));
typedef float f32x4_t  __attribute__((ext_vector_type(4)));

#define LDS_PTR(p) ((__attribute__((address_space(3))) void*)(p))
#define GLB_PTR(p) ((const __attribute__((address_space(1))) void*)(p))

// Problem dims
#define NB   16384   // batch
#define AD   1024    // A dim
#define YD   128     // output dim

// =====================================================================
// Kernel 1: Vt[n][a] = Kp[a, n>>7] * u[2a + (n>>7), n&127]   (bf16, K-major)
// (unchanged — validated)
// =====================================================================
__global__ __launch_bounds__(256) void vt_kernel(
    const float* __restrict__ Kq,   // [1024][2] f32
    const float* __restrict__ U,    // [2048][128] f32
    unsigned short* __restrict__ Vt) // [256][1024] bf16
{
    int idx = blockIdx.x * 256 + threadIdx.x;   // 0 .. 262143
    int n = idx >> 10;
    int a = idx & 1023;
    int j = n >> 7;
    int y = n & 127;
    float k  = Kq[2 * a + j];
    float kp = k * k;
    float uv = U[(size_t)(2 * a + j) * YD + y];
    Vt[idx] = f2b(kp * uv);
}

// =====================================================================
// Kernel 2: FUSED row-solve + GEMM + combine.
// Per block: BM=32 rows, 4 waves (wave w owns rows w*8..w*8+7).
// Phase 1: moments -> closed-form bf iteration (identical math to the
//          validated row_kernel) -> af written as bf16 into a swizzled
//          full-K LDS A-tile (64 KB); bf0/bf1 into an LDS table.
// Phase 2: MFMA GEMM, A from LDS, B (Vt, L2-resident) double-buffered.
// Epilogue: out[m][y] = bf0[m]*G[m][y] + bf1[m]*G[m][y+128] + bias[y].
// LDS: 64 KB (A) + 2*32 KB (B dbuf) + 256 B (bf) -> 1 block/CU.
// =====================================================================
__global__ __launch_bounds__(256, 1) void fused_kernel(
    const float* __restrict__ AT,            // [16384][1024] f32
    const float* __restrict__ Kq,            // [1024][2] f32
    const float* __restrict__ BTv,           // [2] f32
    const unsigned short* __restrict__ Vt,   // [256][1024] bf16
    const float* __restrict__ bias,          // [128] f32
    float* __restrict__ out)                 // [16384][128] f32
{
    __shared__ __align__(16) unsigned short lA[32 * 1024];    // 64 KB, swizzled, full K
    __shared__ __align__(16) unsigned short lB[2][256 * 64];  // 2 x 32 KB
    __shared__ float lbf[32][2];

    const int t    = threadIdx.x;
    const int lane = t & 63;
    const int w    = t >> 6;          // wave id
    const int mtile = blockIdx.x;     // 0..511

    // ---- B staging pointers: slot s holds global chunk (row n = s>>3,
    //      chunk c = (s&7) ^ (n&7)); LDS dest linear, source pre-swizzled.
    const unsigned short* gB[8];
#pragma unroll
    for (int i = 0; i < 8; ++i) {
        int s = i * 256 + t;
        int n = s >> 3;
        int c = (s & 7) ^ (n & 7);
        gB[i] = Vt + (size_t)n * AD + 8 * c;
    }
    // Issue first B chunk (k0=0) NOW — latency hides under phase 1.
#pragma unroll
    for (int i = 0; i < 8; ++i)
        __builtin_amdgcn_global_load_lds(GLB_PTR(gB[i]), LDS_PTR(&lB[0][(i * 256 + t) * 8]), 16, 0, 0);

    // =================== Phase 1: row solve ===================
    // lane owns columns a = c*256 + lane*4 + e, c=0..3, e=0..3
    float kp0[16], kp1[16];
#pragma unroll
    for (int c = 0; c < 4; ++c) {
        int base = c * 256 + lane * 4;
        float4 k0v = *(const float4*)(Kq + 2 * base);      // K[a][0..1], K[a+1][0..1]
        float4 k1v = *(const float4*)(Kq + 2 * base + 4);  // K[a+2..a+3]
        kp0[c * 4 + 0] = k0v.x * k0v.x; kp1[c * 4 + 0] = k0v.y * k0v.y;
        kp0[c * 4 + 1] = k0v.z * k0v.z; kp1[c * 4 + 1] = k0v.w * k0v.w;
        kp0[c * 4 + 2] = k1v.x * k1v.x; kp1[c * 4 + 2] = k1v.y * k1v.y;
        kp0[c * 4 + 3] = k1v.z * k1v.z; kp1[c * 4 + 3] = k1v.w * k1v.w;
    }
    const float bt0 = BTv[0], bt1 = BTv[1];

    // Load all 8 rows up front (32 independent dwordx4 loads -> max MLP).
    float ta[8][16];
    const float* atb = AT + (size_t)(mtile * 32 + w * 8) * AD;
#pragma unroll
    for (int r = 0; r < 8; ++r) {
#pragma unroll
        for (int c = 0; c < 4; ++c) {
            float4 av = *(const float4*)(atb + (size_t)r * AD + c * 256 + lane * 4);
            ta[r][c * 4 + 0] = av.x; ta[r][c * 4 + 1] = av.y;
            ta[r][c * 4 + 2] = av.z; ta[r][c * 4 + 3] = av.w;
        }
    }

#pragma unroll
    for (int r = 0; r < 8; ++r) {
        // moments: 0:M0 1:M1 2:M00 3:M01 4:M11 5:M000 6:M001 7:M011 8:M111
        float M[9];
#pragma unroll
        for (int i2 = 0; i2 < 9; ++i2) M[i2] = 0.f;
#pragma unroll
        for (int e = 0; e < 16; ++e) {
            float tv = ta[r][e], p = kp0[e], q2 = kp1[e];
            float u0 = tv * p, u1 = tv * q2;
            M[0] += u0; M[1] += u1;
            float u00 = u0 * p, u01 = u0 * q2, u11 = u1 * q2;
            M[2] += u00; M[3] += u01; M[4] += u11;
            M[5] += u00 * p; M[6] += u00 * q2; M[7] += u01 * q2; M[8] += u11 * q2;
        }
#pragma unroll
        for (int i2 = 0; i2 < 9; ++i2) {
            for (int mm = 1; mm < 64; mm <<= 1) M[i2] += __shfl_xor(M[i2], mm, 64);
        }

        float bf0 = 0.f, bf1 = 0.f;
#pragma unroll
        for (int it = 0; it < 8; ++it) {
            float q00 = bf0 * bf0, q01 = bf0 * bf1, q11 = bf1 * bf1;
            float s0 = M[0] - (bf0 * M[2] + bf1 * M[3]) + (q00 * M[5] + 2.f * q01 * M[6] + q11 * M[7]);
            float s1 = M[1] - (bf0 * M[3] + bf1 * M[4]) + (q00 * M[6] + 2.f * q01 * M[7] + q11 * M[8]);
            bf0 = bt0 / (1.f + s0);
            bf1 = bt1 / (1.f + s1);
        }
        const int m = w * 8 + r;
        if (lane == 0) { lbf[m][0] = bf0; lbf[m][1] = bf1; }

        // af -> bf16 -> swizzled LDS A-tile.
        // chunk index C = c*32 + (lane>>1); group g = C>>3 = c*4 + (lane>>4);
        // slot-in-group = C&7 = (lane>>1)&7; element addr =
        // (m*128 + g*8 + ((C&7) ^ (m&7)))*8 + (lane&1)*4
#pragma unroll
        for (int c = 0; c < 4; ++c) {
            unsigned short rr[4];
#pragma unroll
            for (int e = 0; e < 4; ++e) {
                int idx = c * 4 + e;
                rr[e] = f2b(ta[r][idx] / (1.f + bf0 * kp0[idx] + bf1 * kp1[idx]));
            }
            int cg = c * 4 + (lane >> 4);
            int cl = (lane >> 1) & 7;
            int off = (m * 128 + cg * 8 + (cl ^ (m & 7))) * 8 + (lane & 1) * 4;
            *(ushort4*)(&lA[off]) = make_ushort4(rr[0], rr[1], rr[2], rr[3]);
        }
    }

    __syncthreads();   // lA/lbf visible; vmcnt(0) drained -> lB[0] ready

    // =================== Phase 2: GEMM ===================
    f32x4_t acc[2][4];
#pragma unroll
    for (int i = 0; i < 2; ++i)
#pragma unroll
        for (int j = 0; j < 4; ++j) acc[i][j] = (f32x4_t){0.f, 0.f, 0.f, 0.f};

    int buf = 0;
    for (int k0 = 0; k0 < AD; k0 += 64) {
        if (k0 + 64 < AD) {
#pragma unroll
            for (int i = 0; i < 8; ++i)
                __builtin_amdgcn_global_load_lds(GLB_PTR(gB[i] + k0 + 64),
                    LDS_PTR(&lB[buf ^ 1][(i * 256 + t) * 8]), 16, 0, 0);
        }
#pragma unroll
        for (int kk = 0; kk < 2; ++kk) {
            const int cq = kk * 4 + (lane >> 4);
            const int rr = lane & 15;
            bf16x8_t fa[2], fb[4];
#pragma unroll
            for (int i = 0; i < 2; ++i) {
                int m = i * 16 + rr;
                fa[i] = *(const bf16x8_t*)(&lA[(m * 128 + (k0 >> 6) * 8 + (cq ^ (m & 7))) * 8]);
            }
#pragma unroll
            for (int j = 0; j < 4; ++j) {
                int n = w * 32 + (j & 1) * 16 + (j >> 1) * 128 + rr;
                fb[j] = *(const bf16x8_t*)(&lB[buf][(n * 8 + (cq ^ (n & 7))) * 8]);
            }
#pragma unroll
            for (int i = 0; i < 2; ++i)
#pragma unroll
                for (int j = 0; j < 4; ++j)
                    acc[i][j] = __builtin_amdgcn_mfma_f32_16x16x32_bf16(fa[i], fb[j], acc[i][j], 0, 0, 0);
        }
        __syncthreads();   // waves done reading lB[buf]; vmcnt(0) -> lB[buf^1] ready
        buf ^= 1;
    }

    // =================== Epilogue ===================
    // C/D layout: col = lane&15 (n), row = (lane>>4)*4 + reg (m)
    const int q = lane >> 4, col = lane & 15;
#pragma unroll
    for (int i = 0; i < 2; ++i) {
        int mloc  = i * 16 + q * 4;
        int mbase = mtile * 32 + mloc;
        float2 bfv[4];
#pragma unroll
        for (int r = 0; r < 4; ++r)
            bfv[r] = *(const float2*)(&lbf[mloc + r][0]);
#pragma unroll
        for (int j = 0; j < 2; ++j) {
            int y = w * 32 + j * 16 + col;
            float bv = bias[y];
#pragma unroll
            for (int r = 0; r < 4; ++r) {
                float val = bfv[r].x * acc[i][j][r] + bfv[r].y * acc[i][j + 2][r] + bv;
                out[(size_t)(mbase + r) * YD + y] = val;
            }
        }
    }
}

// =====================================================================
extern "C" void kernel_launch(void* const* d_in, const int* in_sizes, int n_in,
                              void* d_out, int out_size, void* d_ws, size_t ws_size,
                              hipStream_t stream) {
    const float* AT  = (const float*)d_in[0];  // [16384][1024] f32
    const float* Kq  = (const float*)d_in[1];  // [1024][2] f32
    const float* BTv = (const float*)d_in[2];  // [2] f32
    const float* U   = (const float*)d_in[3];  // [2048][128] f32
    const float* bia = (const float*)d_in[4];  // [128] f32
    float* out = (float*)d_out;

    unsigned short* Vt = (unsigned short*)d_ws;  // 512 KB bf16 [256][1024]

    vt_kernel<<<dim3(1024), dim3(256), 0, stream>>>(Kq, U, Vt);
    fused_kernel<<<dim3(NB / 32), dim3(256), 0, stream>>>(AT, Kq, BTv, Vt, bia, out);
}

// Round 2
// 125.849 us; speedup vs baseline: 1.2111x; 1.2111x over previous
//
#include <hip/hip_runtime.h>

// ---------- helpers ----------
__device__ __forceinline__ unsigned short f2b(float f) {
    unsigned int u = __builtin_bit_cast(unsigned int, f);
    u += 0x7fffu + ((u >> 16) & 1u);   // round-to-nearest-even
    return (unsigned short)(u >> 16);
}
__device__ __forceinline__ float fastrcp(float x) {
    return __builtin_amdgcn_rcpf(x);   // ~1e-7 rel err, invisible under bf16
}

typedef short bf16x8_t __attribute__((ext_vector_type(8)));
typedef float f32x4_t  __attribute__((ext_vector_type(4)));

// Problem dims
#define NB   16384   // batch
#define AD   1024    // A dim
#define YD   128     // output dim

// =====================================================================
// Kernel 1: Vt in FRAGMENT-MAJOR layout.
//   Logical B row n (0..255), col a (0..1023):  val = Kp[a][n>>7]*U[2a+(n>>7)][n&127]
//   Physical: T=n>>4, rr=n&15, CQ=a>>3, e=a&7
//             Vtf[T*16384 + CQ*128 + rr*8 + e]
//   => a wave's MFMA B-fragment (16 rows x 8-elem chunk, cq=kk*4+(lane>>4))
//      is one contiguous, fully-coalesced 1KB load.
// =====================================================================
__global__ __launch_bounds__(256) void vt_kernel(
    const float* __restrict__ Kq,   // [1024][2] f32
    const float* __restrict__ U,    // [2048][128] f32
    unsigned short* __restrict__ Vtf) // [16][128][16][8] bf16
{
    int o  = blockIdx.x * 256 + threadIdx.x;   // output-linear (coalesced writes)
    int T  = o >> 14;
    int CQ = (o >> 7) & 127;
    int rr = (o >> 3) & 15;
    int e  = o & 7;
    int n  = T * 16 + rr;
    int a  = CQ * 8 + e;
    int j  = n >> 7;
    int y  = n & 127;
    float k  = Kq[2 * a + j];
    float uv = U[(size_t)(2 * a + j) * YD + y];
    Vtf[o] = f2b(k * k * uv);
}

// =====================================================================
// Kernel 2: FUSED row-solve + GEMM + combine.
// 256 threads (4 waves), BM=32 rows/block, 512 blocks.
// LDS = 64KB A-tile + 256B bf table -> 2 blocks/CU (8 waves/CU, 2/SIMD).
// Phase 1: moments -> closed-form bf solve (rcp) -> af bf16 into swizzled
//          full-K LDS A-tile; bf0/bf1 into LDS table.  (validated math)
// Phase 2: barrier-free k-loop: A frags from LDS, B frags register-double-
//          buffered straight from L2 (fragment-major Vtf, coalesced).
// =====================================================================
__global__ __launch_bounds__(256, 2) void fused_kernel(
    const float* __restrict__ AT,            // [16384][1024] f32
    const float* __restrict__ Kq,            // [1024][2] f32
    const float* __restrict__ BTv,           // [2] f32
    const unsigned short* __restrict__ Vtf,  // fragment-major bf16
    const float* __restrict__ bias,          // [128] f32
    float* __restrict__ out)                 // [16384][128] f32
{
    __shared__ __align__(16) unsigned short lA[32 * 1024];    // 64 KB
    __shared__ float lbf[32][2];

    const int t    = threadIdx.x;
    const int lane = t & 63;
    const int w    = t >> 6;          // wave id
    const int mtile = blockIdx.x;     // 0..511

    // =================== Phase 1: row solve ===================
    // lane owns columns a = c*256 + lane*4 + e, c=0..3, e=0..3
    float kp0[16], kp1[16];
#pragma unroll
    for (int c = 0; c < 4; ++c) {
        int base = c * 256 + lane * 4;
        float4 k0v = *(const float4*)(Kq + 2 * base);
        float4 k1v = *(const float4*)(Kq + 2 * base + 4);
        kp0[c * 4 + 0] = k0v.x * k0v.x; kp1[c * 4 + 0] = k0v.y * k0v.y;
        kp0[c * 4 + 1] = k0v.z * k0v.z; kp1[c * 4 + 1] = k0v.w * k0v.w;
        kp0[c * 4 + 2] = k1v.x * k1v.x; kp1[c * 4 + 2] = k1v.y * k1v.y;
        kp0[c * 4 + 3] = k1v.z * k1v.z; kp1[c * 4 + 3] = k1v.w * k1v.w;
    }
    const float bt0 = BTv[0], bt1 = BTv[1];

    // Load all 8 rows up front (32 independent dwordx4 loads -> max MLP).
    float ta[8][16];
    const float* atb = AT + (size_t)(mtile * 32 + w * 8) * AD;
#pragma unroll
    for (int r = 0; r < 8; ++r) {
#pragma unroll
        for (int c = 0; c < 4; ++c) {
            float4 av = *(const float4*)(atb + (size_t)r * AD + c * 256 + lane * 4);
            ta[r][c * 4 + 0] = av.x; ta[r][c * 4 + 1] = av.y;
            ta[r][c * 4 + 2] = av.z; ta[r][c * 4 + 3] = av.w;
        }
    }

#pragma unroll
    for (int r = 0; r < 8; ++r) {
        // moments: 0:M0 1:M1 2:M00 3:M01 4:M11 5:M000 6:M001 7:M011 8:M111
        float M[9];
#pragma unroll
        for (int i2 = 0; i2 < 9; ++i2) M[i2] = 0.f;
#pragma unroll
        for (int e = 0; e < 16; ++e) {
            float tv = ta[r][e], p = kp0[e], q2 = kp1[e];
            float u0 = tv * p, u1 = tv * q2;
            M[0] += u0; M[1] += u1;
            float u00 = u0 * p, u01 = u0 * q2, u11 = u1 * q2;
            M[2] += u00; M[3] += u01; M[4] += u11;
            M[5] += u00 * p; M[6] += u00 * q2; M[7] += u01 * q2; M[8] += u11 * q2;
        }
#pragma unroll
        for (int i2 = 0; i2 < 9; ++i2) {
            for (int mm = 1; mm < 64; mm <<= 1) M[i2] += __shfl_xor(M[i2], mm, 64);
        }

        float bf0 = 0.f, bf1 = 0.f;
#pragma unroll
        for (int it = 0; it < 8; ++it) {
            float q00 = bf0 * bf0, q01 = bf0 * bf1, q11 = bf1 * bf1;
            float s0 = M[0] - (bf0 * M[2] + bf1 * M[3]) + (q00 * M[5] + 2.f * q01 * M[6] + q11 * M[7]);
            float s1 = M[1] - (bf0 * M[3] + bf1 * M[4]) + (q00 * M[6] + 2.f * q01 * M[7] + q11 * M[8]);
            bf0 = bt0 * fastrcp(1.f + s0);
            bf1 = bt1 * fastrcp(1.f + s1);
        }
        const int m = w * 8 + r;
        if (lane == 0) { lbf[m][0] = bf0; lbf[m][1] = bf1; }

        // af -> bf16 -> swizzled LDS A-tile (identical layout to validated kernel)
#pragma unroll
        for (int c = 0; c < 4; ++c) {
            unsigned short rv[4];
#pragma unroll
            for (int e = 0; e < 4; ++e) {
                int idx = c * 4 + e;
                rv[e] = f2b(ta[r][idx] * fastrcp(1.f + bf0 * kp0[idx] + bf1 * kp1[idx]));
            }
            int cg = c * 4 + (lane >> 4);
            int cl = (lane >> 1) & 7;
            int off = (m * 128 + cg * 8 + (cl ^ (m & 7))) * 8 + (lane & 1) * 4;
            *(ushort4*)(&lA[off]) = make_ushort4(rv[0], rv[1], rv[2], rv[3]);
        }
    }

    __syncthreads();   // the ONLY barrier: lA/lbf now visible to all waves

    // =================== Phase 2: barrier-free GEMM ===================
    const int rr = lane & 15;      // row-in-tile
    const int hb = lane >> 4;      // quarter-wave
    const int rx = rr & 7;         // A-swizzle key ((i*16+rr)&7 == rr&7)

    // wave w owns n-tiles: {2w, 2w+1} (y) and {2w+8, 2w+9} (y+128)
    const unsigned short* pB = Vtf + w * 32768 + hb * 128 + rr * 8;

    f32x4_t acc[2][4];
#pragma unroll
    for (int i = 0; i < 2; ++i)
#pragma unroll
        for (int j = 0; j < 4; ++j) acc[i][j] = (f32x4_t){0.f, 0.f, 0.f, 0.f};

    bf16x8_t fbA[8], fbB[8];

    auto loadB = [&](bf16x8_t* fb, int k0) {
#pragma unroll
        for (int kk = 0; kk < 2; ++kk) {
            int ke = k0 * 16 + kk * 512;          // elem offset for this K-slice
            fb[kk * 4 + 0] = *(const bf16x8_t*)(pB + ke);            // tile 2w
            fb[kk * 4 + 1] = *(const bf16x8_t*)(pB + ke + 16384);    // tile 2w+1
            fb[kk * 4 + 2] = *(const bf16x8_t*)(pB + ke + 131072);   // tile 2w+8
            fb[kk * 4 + 3] = *(const bf16x8_t*)(pB + ke + 147456);   // tile 2w+9
        }
    };
    auto compute = [&](const bf16x8_t* fb, int k0) {
#pragma unroll
        for (int kk = 0; kk < 2; ++kk) {
            const int cq = kk * 4 + hb;
            bf16x8_t fa[2];
#pragma unroll
            for (int i = 0; i < 2; ++i)
                fa[i] = *(const bf16x8_t*)(&lA[(((i * 16 + rr) * 128) + (k0 >> 6) * 8 + (cq ^ rx)) * 8]);
#pragma unroll
            for (int i = 0; i < 2; ++i)
#pragma unroll
                for (int j = 0; j < 4; ++j)
                    acc[i][j] = __builtin_amdgcn_mfma_f32_16x16x32_bf16(fa[i], fb[kk * 4 + j], acc[i][j], 0, 0, 0);
        }
    };

    loadB(fbA, 0);
#pragma unroll 1
    for (int k0 = 0; k0 < AD; k0 += 128) {
        loadB(fbB, k0 + 64);
        __builtin_amdgcn_s_setprio(1);
        compute(fbA, k0);
        __builtin_amdgcn_s_setprio(0);
        if (k0 + 128 < AD) loadB(fbA, k0 + 128);
        __builtin_amdgcn_s_setprio(1);
        compute(fbB, k0 + 64);
        __builtin_amdgcn_s_setprio(0);
    }

    // =================== Epilogue ===================
    // C/D layout: col = lane&15 (n), row = (lane>>4)*4 + reg (m)
    const int q = hb, col = rr;
#pragma unroll
    for (int i = 0; i < 2; ++i) {
        int mloc  = i * 16 + q * 4;
        int mbase = mtile * 32 + mloc;
        float2 bfv[4];
#pragma unroll
        for (int r = 0; r < 4; ++r)
            bfv[r] = *(const float2*)(&lbf[mloc + r][0]);
#pragma unroll
        for (int j = 0; j < 2; ++j) {
            int y = w * 32 + j * 16 + col;
            float bv = bias[y];
#pragma unroll
            for (int r = 0; r < 4; ++r) {
                float val = bfv[r].x * acc[i][j][r] + bfv[r].y * acc[i][j + 2][r] + bv;
                out[(size_t)(mbase + r) * YD + y] = val;
            }
        }
    }
}

// =====================================================================
extern "C" void kernel_launch(void* const* d_in, const int* in_sizes, int n_in,
                              void* d_out, int out_size, void* d_ws, size_t ws_size,
                              hipStream_t stream) {
    const float* AT  = (const float*)d_in[0];  // [16384][1024] f32
    const float* Kq  = (const float*)d_in[1];  // [1024][2] f32
    const float* BTv = (const float*)d_in[2];  // [2] f32
    const float* U   = (const float*)d_in[3];  // [2048][128] f32
    const float* bia = (const float*)d_in[4];  // [128] f32
    float* out = (float*)d_out;

    unsigned short* Vtf = (unsigned short*)d_ws;  // 512 KB bf16 fragment-major

    vt_kernel<<<dim3(1024), dim3(256), 0, stream>>>(Kq, U, Vtf);
    fused_kernel<<<dim3(NB / 32), dim3(256), 0, stream>>>(AT, Kq, BTv, Vtf, bia, out);
}

// Round 3
// 122.796 us; speedup vs baseline: 1.2412x; 1.0249x over previous
//
#include <hip/hip_runtime.h>

// ---------- helpers ----------
__device__ __forceinline__ unsigned short f2b(float f) {
    unsigned int u = __builtin_bit_cast(unsigned int, f);
    u += 0x7fffu + ((u >> 16) & 1u);   // round-to-nearest-even
    return (unsigned short)(u >> 16);
}
__device__ __forceinline__ float fastrcp(float x) {
    return __builtin_amdgcn_rcpf(x);   // ~1e-7 rel err, invisible under bf16
}

typedef short bf16x8_t __attribute__((ext_vector_type(8)));
typedef float f32x4_t  __attribute__((ext_vector_type(4)));

// Problem dims
#define NB   16384   // batch
#define AD   1024    // A dim
#define YD   128     // output dim

// =====================================================================
// Kernel 1: Vt in FRAGMENT-MAJOR layout (unchanged — validated).
//   Logical B row n (0..255), col a (0..1023):  val = Kp[a][n>>7]*U[2a+(n>>7)][n&127]
//   Physical: T=n>>4, rr=n&15, CQ=a>>3, e=a&7
//             Vtf[T*16384 + CQ*128 + rr*8 + e]
// =====================================================================
__global__ __launch_bounds__(256) void vt_kernel(
    const float* __restrict__ Kq,   // [1024][2] f32
    const float* __restrict__ U,    // [2048][128] f32
    unsigned short* __restrict__ Vtf) // [16][128][16][8] bf16
{
    int o  = blockIdx.x * 256 + threadIdx.x;
    int T  = o >> 14;
    int CQ = (o >> 7) & 127;
    int rr = (o >> 3) & 15;
    int e  = o & 7;
    int n  = T * 16 + rr;
    int a  = CQ * 8 + e;
    int j  = n >> 7;
    int y  = n & 127;
    float k  = Kq[2 * a + j];
    float uv = U[(size_t)(2 * a + j) * YD + y];
    Vtf[o] = f2b(k * k * uv);
}

// =====================================================================
// Kernel 2: FUSED row-solve + GEMM + combine.
// 512 threads (8 waves), BM=32 rows/block, 512 blocks.
// LDS = 64KB A-tile + 256B bf -> 2 blocks/CU = 16 waves/CU = 4 waves/SIMD
// (VGPR capped at 128 via __launch_bounds__(512,4)).
// Phase 1: wave w owns rows w*4..w*4+3, processed serially with a 2-row
//          register double-buffer (static indexing). Math identical to
//          the validated version (moments -> shuffle reduce -> 8-iter
//          closed-form solve -> af bf16 into swizzled LDS A-tile).
// Phase 2: barrier-free k-loop; wave w owns n-tiles {w, w+8} (the
//          (y, y+128) pair); A frags from LDS, B frags register-dbuf
//          straight from L2 (fragment-major Vtf).
// =====================================================================
__global__ __launch_bounds__(512, 4) void fused_kernel(
    const float* __restrict__ AT,            // [16384][1024] f32
    const float* __restrict__ Kq,            // [1024][2] f32
    const float* __restrict__ BTv,           // [2] f32
    const unsigned short* __restrict__ Vtf,  // fragment-major bf16
    const float* __restrict__ bias,          // [128] f32
    float* __restrict__ out)                 // [16384][128] f32
{
    __shared__ __align__(16) unsigned short lA[32 * 1024];    // 64 KB
    __shared__ float lbf[32][2];

    const int t    = threadIdx.x;
    const int lane = t & 63;
    const int w    = t >> 6;          // wave id 0..7
    const int mtile = blockIdx.x;     // 0..511

    // =================== Phase 1: row solve (4 rows/wave) ===================
    // lane owns columns a = c*256 + lane*4 + e, c=0..3, e=0..3
    float kp0[16], kp1[16];
#pragma unroll
    for (int c = 0; c < 4; ++c) {
        int base = c * 256 + lane * 4;
        float4 k0v = *(const float4*)(Kq + 2 * base);
        float4 k1v = *(const float4*)(Kq + 2 * base + 4);
        kp0[c * 4 + 0] = k0v.x * k0v.x; kp1[c * 4 + 0] = k0v.y * k0v.y;
        kp0[c * 4 + 1] = k0v.z * k0v.z; kp1[c * 4 + 1] = k0v.w * k0v.w;
        kp0[c * 4 + 2] = k1v.x * k1v.x; kp1[c * 4 + 2] = k1v.y * k1v.y;
        kp0[c * 4 + 3] = k1v.z * k1v.z; kp1[c * 4 + 3] = k1v.w * k1v.w;
    }
    const float bt0 = BTv[0], bt1 = BTv[1];

    const float* atb = AT + (size_t)(mtile * 32 + w * 4) * AD;

    float ta[2][16];   // 2-row double buffer, statically indexed (full unroll)
    // prologue: load row 0 into buf 0
#pragma unroll
    for (int c = 0; c < 4; ++c) {
        float4 av = *(const float4*)(atb + c * 256 + lane * 4);
        ta[0][c * 4 + 0] = av.x; ta[0][c * 4 + 1] = av.y;
        ta[0][c * 4 + 2] = av.z; ta[0][c * 4 + 3] = av.w;
    }

#pragma unroll
    for (int r = 0; r < 4; ++r) {
        const int cur = r & 1, nxt = cur ^ 1;
        // prefetch next row into the other buffer (hides under this row's math)
        if (r < 3) {
#pragma unroll
            for (int c = 0; c < 4; ++c) {
                float4 av = *(const float4*)(atb + (size_t)(r + 1) * AD + c * 256 + lane * 4);
                ta[nxt][c * 4 + 0] = av.x; ta[nxt][c * 4 + 1] = av.y;
                ta[nxt][c * 4 + 2] = av.z; ta[nxt][c * 4 + 3] = av.w;
            }
        }

        // moments: 0:M0 1:M1 2:M00 3:M01 4:M11 5:M000 6:M001 7:M011 8:M111
        float M[9];
#pragma unroll
        for (int i2 = 0; i2 < 9; ++i2) M[i2] = 0.f;
#pragma unroll
        for (int e = 0; e < 16; ++e) {
            float tv = ta[cur][e], p = kp0[e], q2 = kp1[e];
            float u0 = tv * p, u1 = tv * q2;
            M[0] += u0; M[1] += u1;
            float u00 = u0 * p, u01 = u0 * q2, u11 = u1 * q2;
            M[2] += u00; M[3] += u01; M[4] += u11;
            M[5] += u00 * p; M[6] += u00 * q2; M[7] += u01 * q2; M[8] += u11 * q2;
        }
#pragma unroll
        for (int i2 = 0; i2 < 9; ++i2) {
            for (int mm = 1; mm < 64; mm <<= 1) M[i2] += __shfl_xor(M[i2], mm, 64);
        }

        float bf0 = 0.f, bf1 = 0.f;
#pragma unroll
        for (int it = 0; it < 8; ++it) {
            float q00 = bf0 * bf0, q01 = bf0 * bf1, q11 = bf1 * bf1;
            float s0 = M[0] - (bf0 * M[2] + bf1 * M[3]) + (q00 * M[5] + 2.f * q01 * M[6] + q11 * M[7]);
            float s1 = M[1] - (bf0 * M[3] + bf1 * M[4]) + (q00 * M[6] + 2.f * q01 * M[7] + q11 * M[8]);
            bf0 = bt0 * fastrcp(1.f + s0);
            bf1 = bt1 * fastrcp(1.f + s1);
        }
        const int m = w * 4 + r;
        if (lane == 0) { lbf[m][0] = bf0; lbf[m][1] = bf1; }

        // af -> bf16 -> swizzled LDS A-tile (identical layout to validated kernel)
#pragma unroll
        for (int c = 0; c < 4; ++c) {
            unsigned short rv[4];
#pragma unroll
            for (int e = 0; e < 4; ++e) {
                int idx = c * 4 + e;
                rv[e] = f2b(ta[cur][idx] * fastrcp(1.f + bf0 * kp0[idx] + bf1 * kp1[idx]));
            }
            int cg = c * 4 + (lane >> 4);
            int cl = (lane >> 1) & 7;
            int off = (m * 128 + cg * 8 + (cl ^ (m & 7))) * 8 + (lane & 1) * 4;
            *(ushort4*)(&lA[off]) = make_ushort4(rv[0], rv[1], rv[2], rv[3]);
        }
    }

    __syncthreads();   // the ONLY barrier: lA/lbf now visible to all waves

    // =================== Phase 2: barrier-free GEMM ===================
    const int rr = lane & 15;      // row-in-tile
    const int hb = lane >> 4;      // quarter-wave
    const int rx = rr & 7;         // A-swizzle key

    // wave w owns n-tiles {w, w+8}: y = w*16+col and y+128
    const unsigned short* pB = Vtf + w * 16384 + hb * 128 + rr * 8;

    f32x4_t acc[2][2];
#pragma unroll
    for (int i = 0; i < 2; ++i)
#pragma unroll
        for (int j = 0; j < 2; ++j) acc[i][j] = (f32x4_t){0.f, 0.f, 0.f, 0.f};

    bf16x8_t fbA[4], fbB[4];

    auto loadB = [&](bf16x8_t* fb, int k0) {
#pragma unroll
        for (int kk = 0; kk < 2; ++kk) {
            int ke = k0 * 16 + kk * 512;          // elem offset for this K-slice
            fb[kk * 2 + 0] = *(const bf16x8_t*)(pB + ke);            // tile w
            fb[kk * 2 + 1] = *(const bf16x8_t*)(pB + ke + 131072);   // tile w+8
        }
    };
    auto compute = [&](const bf16x8_t* fb, int k0) {
#pragma unroll
        for (int kk = 0; kk < 2; ++kk) {
            const int cq = kk * 4 + hb;
            bf16x8_t fa[2];
#pragma unroll
            for (int i = 0; i < 2; ++i)
                fa[i] = *(const bf16x8_t*)(&lA[(((i * 16 + rr) * 128) + (k0 >> 6) * 8 + (cq ^ rx)) * 8]);
#pragma unroll
            for (int i = 0; i < 2; ++i)
#pragma unroll
                for (int j = 0; j < 2; ++j)
                    acc[i][j] = __builtin_amdgcn_mfma_f32_16x16x32_bf16(fa[i], fb[kk * 2 + j], acc[i][j], 0, 0, 0);
        }
    };

    loadB(fbA, 0);
#pragma unroll 1
    for (int k0 = 0; k0 < AD; k0 += 128) {
        loadB(fbB, k0 + 64);
        __builtin_amdgcn_s_setprio(1);
        compute(fbA, k0);
        __builtin_amdgcn_s_setprio(0);
        if (k0 + 128 < AD) loadB(fbA, k0 + 128);
        __builtin_amdgcn_s_setprio(1);
        compute(fbB, k0 + 64);
        __builtin_amdgcn_s_setprio(0);
    }

    // =================== Epilogue ===================
    // C/D layout: col = lane&15 (n), row = (lane>>4)*4 + reg (m)
    const int q = hb, col = rr;
#pragma unroll
    for (int i = 0; i < 2; ++i) {
        int mloc  = i * 16 + q * 4;
        int mbase = mtile * 32 + mloc;
        float2 bfv[4];
#pragma unroll
        for (int r = 0; r < 4; ++r)
            bfv[r] = *(const float2*)(&lbf[mloc + r][0]);
        int y = w * 16 + col;
        float bv = bias[y];
#pragma unroll
        for (int r = 0; r < 4; ++r) {
            float val = bfv[r].x * acc[i][0][r] + bfv[r].y * acc[i][1][r] + bv;
            out[(size_t)(mbase + r) * YD + y] = val;
        }
    }
}

// =====================================================================
extern "C" void kernel_launch(void* const* d_in, const int* in_sizes, int n_in,
                              void* d_out, int out_size, void* d_ws, size_t ws_size,
                              hipStream_t stream) {
    const float* AT  = (const float*)d_in[0];  // [16384][1024] f32
    const float* Kq  = (const float*)d_in[1];  // [1024][2] f32
    const float* BTv = (const float*)d_in[2];  // [2] f32
    const float* U   = (const float*)d_in[3];  // [2048][128] f32
    const float* bia = (const float*)d_in[4];  // [128] f32
    float* out = (float*)d_out;

    unsigned short* Vtf = (unsigned short*)d_ws;  // 512 KB bf16 fragment-major

    vt_kernel<<<dim3(1024), dim3(256), 0, stream>>>(Kq, U, Vtf);
    fused_kernel<<<dim3(NB / 32), dim3(512), 0, stream>>>(AT, Kq, BTv, Vtf, bia, out);
}

// Round 4
// 118.826 us; speedup vs baseline: 1.2826x; 1.0334x over previous
//
#include <hip/hip_runtime.h>

// ---------- helpers ----------
__device__ __forceinline__ unsigned short f2b(float f) {
    unsigned int u = __builtin_bit_cast(unsigned int, f);
    u += 0x7fffu + ((u >> 16) & 1u);   // round-to-nearest-even
    return (unsigned short)(u >> 16);
}
__device__ __forceinline__ float fastrcp(float x) {
    return __builtin_amdgcn_rcpf(x);   // ~1e-7 rel err, invisible under bf16
}
// packed f32x2 -> bf16x2 (RTNE, same rounding as f2b), 1 instruction
__device__ __forceinline__ unsigned int cvt_pk_bf16(float lo, float hi) {
    unsigned int r;
    asm("v_cvt_pk_bf16_f32 %0, %1, %2" : "=v"(r) : "v"(lo), "v"(hi));
    return r;
}
// DPP wave64 sum: after chain, lane 63 holds the full sum; broadcast via readlane.
template<int CTRL>
__device__ __forceinline__ float dpp_add(float x) {
    int s = __builtin_amdgcn_update_dpp(0, __builtin_bit_cast(int, x), CTRL, 0xf, 0xf, true);
    return x + __builtin_bit_cast(float, s);
}
__device__ __forceinline__ float wave_sum_bcast(float x) {
    x = dpp_add<0x111>(x);   // row_shr:1
    x = dpp_add<0x112>(x);   // row_shr:2
    x = dpp_add<0x114>(x);   // row_shr:4
    x = dpp_add<0x118>(x);   // row_shr:8  -> lane 15/31/47/63 = row sums
    x = dpp_add<0x142>(x);   // row_bcast:15
    x = dpp_add<0x143>(x);   // row_bcast:31 -> lane 63 = total
    return __builtin_bit_cast(float,
        __builtin_amdgcn_readlane(__builtin_bit_cast(int, x), 63));
}

typedef short bf16x8_t __attribute__((ext_vector_type(8)));
typedef float f32x4_t  __attribute__((ext_vector_type(4)));

// Problem dims
#define NB   16384   // batch
#define AD   1024    // A dim
#define YD   128     // output dim

// =====================================================================
// Kernel 1: Vt in FRAGMENT-MAJOR layout (unchanged — validated).
//   Logical B row n (0..255), col a (0..1023):  val = Kp[a][n>>7]*U[2a+(n>>7)][n&127]
//   Physical: T=n>>4, rr=n&15, CQ=a>>3, e=a&7
//             Vtf[T*16384 + CQ*128 + rr*8 + e]
// =====================================================================
__global__ __launch_bounds__(256) void vt_kernel(
    const float* __restrict__ Kq,   // [1024][2] f32
    const float* __restrict__ U,    // [2048][128] f32
    unsigned short* __restrict__ Vtf) // [16][128][16][8] bf16
{
    int o  = blockIdx.x * 256 + threadIdx.x;
    int T  = o >> 14;
    int CQ = (o >> 7) & 127;
    int rr = (o >> 3) & 15;
    int e  = o & 7;
    int n  = T * 16 + rr;
    int a  = CQ * 8 + e;
    int j  = n >> 7;
    int y  = n & 127;
    float k  = Kq[2 * a + j];
    float uv = U[(size_t)(2 * a + j) * YD + y];
    Vtf[o] = f2b(k * k * uv);
}

// =====================================================================
// Kernel 2: FUSED row-solve + GEMM + combine.
// 512 threads (8 waves), BM=32 rows/block, 512 blocks.
// LDS = 64KB A-tile + 256B bf -> 2 blocks/CU = 4 waves/SIMD.
// Phase 1: wave w owns rows w*4..w*4+3 (2-row reg dbuf). Moments ->
//          DPP wave-sum (no DS ops) -> 8-iter closed-form solve ->
//          af bf16 via v_cvt_pk_bf16_f32 into swizzled LDS A-tile.
// Phase 2: barrier-free k-loop; wave w: h=w>>2 owns m-rows h*16..+15,
//          q=w&3 owns n-tiles {2q,2q+1,2q+8,2q+9}. A frags from LDS
//          (1 ds_read/kk), B frags reg-dbuf straight from L2.
// Epilogue: wave writes 32 CONTIGUOUS cols (full 128B lines).
// =====================================================================
__global__ __launch_bounds__(512, 4) void fused_kernel(
    const float* __restrict__ AT,            // [16384][1024] f32
    const float* __restrict__ Kq,            // [1024][2] f32
    const float* __restrict__ BTv,           // [2] f32
    const unsigned short* __restrict__ Vtf,  // fragment-major bf16
    const float* __restrict__ bias,          // [128] f32
    float* __restrict__ out)                 // [16384][128] f32
{
    __shared__ __align__(16) unsigned short lA[32 * 1024];    // 64 KB
    __shared__ float lbf[32][2];

    const int t    = threadIdx.x;
    const int lane = t & 63;
    const int w    = t >> 6;          // wave id 0..7
    const int mtile = blockIdx.x;     // 0..511

    // =================== Phase 1: row solve (4 rows/wave) ===================
    // lane owns columns a = c*256 + lane*4 + e, c=0..3, e=0..3
    float kp0[16], kp1[16];
#pragma unroll
    for (int c = 0; c < 4; ++c) {
        int base = c * 256 + lane * 4;
        float4 k0v = *(const float4*)(Kq + 2 * base);
        float4 k1v = *(const float4*)(Kq + 2 * base + 4);
        kp0[c * 4 + 0] = k0v.x * k0v.x; kp1[c * 4 + 0] = k0v.y * k0v.y;
        kp0[c * 4 + 1] = k0v.z * k0v.z; kp1[c * 4 + 1] = k0v.w * k0v.w;
        kp0[c * 4 + 2] = k1v.x * k1v.x; kp1[c * 4 + 2] = k1v.y * k1v.y;
        kp0[c * 4 + 3] = k1v.z * k1v.z; kp1[c * 4 + 3] = k1v.w * k1v.w;
    }
    const float bt0 = BTv[0], bt1 = BTv[1];

    const float* atb = AT + (size_t)(mtile * 32 + w * 4) * AD;

    float ta[2][16];   // 2-row double buffer, statically indexed (full unroll)
#pragma unroll
    for (int c = 0; c < 4; ++c) {
        float4 av = *(const float4*)(atb + c * 256 + lane * 4);
        ta[0][c * 4 + 0] = av.x; ta[0][c * 4 + 1] = av.y;
        ta[0][c * 4 + 2] = av.z; ta[0][c * 4 + 3] = av.w;
    }

#pragma unroll
    for (int r = 0; r < 4; ++r) {
        const int cur = r & 1, nxt = cur ^ 1;
        if (r < 3) {
#pragma unroll
            for (int c = 0; c < 4; ++c) {
                float4 av = *(const float4*)(atb + (size_t)(r + 1) * AD + c * 256 + lane * 4);
                ta[nxt][c * 4 + 0] = av.x; ta[nxt][c * 4 + 1] = av.y;
                ta[nxt][c * 4 + 2] = av.z; ta[nxt][c * 4 + 3] = av.w;
            }
        }

        // moments: 0:M0 1:M1 2:M00 3:M01 4:M11 5:M000 6:M001 7:M011 8:M111
        float M[9];
#pragma unroll
        for (int i2 = 0; i2 < 9; ++i2) M[i2] = 0.f;
#pragma unroll
        for (int e = 0; e < 16; ++e) {
            float tv = ta[cur][e], p = kp0[e], q2 = kp1[e];
            float u0 = tv * p, u1 = tv * q2;
            M[0] += u0; M[1] += u1;
            float u00 = u0 * p, u01 = u0 * q2, u11 = u1 * q2;
            M[2] += u00; M[3] += u01; M[4] += u11;
            M[5] += u00 * p; M[6] += u00 * q2; M[7] += u01 * q2; M[8] += u11 * q2;
        }
        // DPP reduce (no LDS/DS ops), result uniform via readlane
#pragma unroll
        for (int i2 = 0; i2 < 9; ++i2) M[i2] = wave_sum_bcast(M[i2]);

        float bf0 = 0.f, bf1 = 0.f;
#pragma unroll
        for (int it = 0; it < 8; ++it) {
            float q00 = bf0 * bf0, q01 = bf0 * bf1, q11 = bf1 * bf1;
            float s0 = M[0] - (bf0 * M[2] + bf1 * M[3]) + (q00 * M[5] + 2.f * q01 * M[6] + q11 * M[7]);
            float s1 = M[1] - (bf0 * M[3] + bf1 * M[4]) + (q00 * M[6] + 2.f * q01 * M[7] + q11 * M[8]);
            bf0 = bt0 * fastrcp(1.f + s0);
            bf1 = bt1 * fastrcp(1.f + s1);
        }
        const int m = w * 4 + r;
        if (lane == 0) { lbf[m][0] = bf0; lbf[m][1] = bf1; }

        // af -> bf16 (cvt_pk, RTNE) -> swizzled LDS A-tile (layout unchanged)
#pragma unroll
        for (int c = 0; c < 4; ++c) {
            float v[4];
#pragma unroll
            for (int e = 0; e < 4; ++e) {
                int idx = c * 4 + e;
                v[e] = ta[cur][idx] * fastrcp(1.f + bf0 * kp0[idx] + bf1 * kp1[idx]);
            }
            uint2 pk;
            pk.x = cvt_pk_bf16(v[0], v[1]);
            pk.y = cvt_pk_bf16(v[2], v[3]);
            int cg = c * 4 + (lane >> 4);
            int cl = (lane >> 1) & 7;
            int off = (m * 128 + cg * 8 + (cl ^ (m & 7))) * 8 + (lane & 1) * 4;
            *(uint2*)(&lA[off]) = pk;
        }
    }

    __syncthreads();   // the ONLY barrier: lA/lbf now visible to all waves

    // =================== Phase 2: barrier-free GEMM ===================
    const int rr = lane & 15;      // row/col within 16-tile
    const int hb = lane >> 4;      // quarter-wave
    const int q  = w & 3;          // n-quad: tiles {2q, 2q+1, 2q+8, 2q+9}
    const int h  = w >> 2;         // m-half: rows h*16 .. h*16+15
    const int rx = rr & 7;         // A-swizzle key ((h*16+rr)&7 == rr&7)

    const int lanePart = hb * 128 + rr * 8;                  // lane-varying part
    const unsigned short* bq = Vtf + (size_t)(2 * q) * 16384 + lanePart;

    f32x4_t acc[4];
#pragma unroll
    for (int j = 0; j < 4; ++j) acc[j] = (f32x4_t){0.f, 0.f, 0.f, 0.f};

    bf16x8_t fbA[4], fbB[4];

    auto loadB = [&](bf16x8_t* fb, int k0, int kk) {
        int ke = k0 * 16 + kk * 512;              // uniform elem offset
        fb[0] = *(const bf16x8_t*)(bq + ke);            // tile 2q
        fb[1] = *(const bf16x8_t*)(bq + ke + 16384);    // tile 2q+1
        fb[2] = *(const bf16x8_t*)(bq + ke + 131072);   // tile 2q+8
        fb[3] = *(const bf16x8_t*)(bq + ke + 147456);   // tile 2q+9
    };
    auto compute = [&](const bf16x8_t* fb, int k0, int kk) {
        const int cq = kk * 4 + hb;
        bf16x8_t fa = *(const bf16x8_t*)(
            &lA[(((h * 16 + rr) * 128) + (k0 >> 6) * 8 + (cq ^ rx)) * 8]);
#pragma unroll
        for (int j = 0; j < 4; ++j)
            acc[j] = __builtin_amdgcn_mfma_f32_16x16x32_bf16(fa, fb[j], acc[j], 0, 0, 0);
    };

    loadB(fbA, 0, 0);
    loadB(fbB, 0, 1);
#pragma unroll 1
    for (int k0 = 0; k0 < AD; k0 += 64) {
        __builtin_amdgcn_s_setprio(1);
        compute(fbA, k0, 0);
        __builtin_amdgcn_s_setprio(0);
        if (k0 + 64 < AD) loadB(fbA, k0 + 64, 0);
        __builtin_amdgcn_s_setprio(1);
        compute(fbB, k0, 1);
        __builtin_amdgcn_s_setprio(0);
        if (k0 + 64 < AD) loadB(fbB, k0 + 64, 1);
    }

    // =================== Epilogue ===================
    // C/D layout: col = lane&15 (n within tile), row = (lane>>4)*4 + reg.
    // acc[jj] (tile 2q+jj, y-cols) pairs with acc[jj+2] (tile 2q+8+jj, y+128).
    // Wave writes cols q*32 .. q*32+31: full 128B lines.
    const int mloc  = h * 16 + hb * 4;
    const int mbase = mtile * 32 + mloc;
    float2 bfv[4];
#pragma unroll
    for (int r = 0; r < 4; ++r)
        bfv[r] = *(const float2*)(&lbf[mloc + r][0]);
#pragma unroll
    for (int jj = 0; jj < 2; ++jj) {
        int y = q * 32 + jj * 16 + rr;
        float bv = bias[y];
#pragma unroll
        for (int r = 0; r < 4; ++r) {
            float val = bfv[r].x * acc[jj][r] + bfv[r].y * acc[jj + 2][r] + bv;
            out[(size_t)(mbase + r) * YD + y] = val;
        }
    }
}

// =====================================================================
extern "C" void kernel_launch(void* const* d_in, const int* in_sizes, int n_in,
                              void* d_out, int out_size, void* d_ws, size_t ws_size,
                              hipStream_t stream) {
    const float* AT  = (const float*)d_in[0];  // [16384][1024] f32
    const float* Kq  = (const float*)d_in[1];  // [1024][2] f32
    const float* BTv = (const float*)d_in[2];  // [2] f32
    const float* U   = (const float*)d_in[3];  // [2048][128] f32
    const float* bia = (const float*)d_in[4];  // [128] f32
    float* out = (float*)d_out;

    unsigned short* Vtf = (unsigned short*)d_ws;  // 512 KB bf16 fragment-major

    vt_kernel<<<dim3(1024), dim3(256), 0, stream>>>(Kq, U, Vtf);
    fused_kernel<<<dim3(NB / 32), dim3(512), 0, stream>>>(AT, Kq, BTv, Vtf, bia, out);
}